// Round 8
// baseline (206.273 us; speedup 1.0000x reference)
//
#include <hip/hip_runtime.h>

#define NROI 1000
#define NCLS 81
#define NB   8
#define NLANE (NB*NCLS)        // 648 = 8 XCDs * 81
#define MAXM 1024
#define MAXKEEP 200
#define SCORE_T 0.5f
#define NT 512
#define NW 8                   // waves per block
#define NBKT 2048              // 11-bit sort buckets
#define HBITS 13
#define HSIZE (1<<HBITS)       // 8192 merge buckets
#define SCAP 1024

typedef unsigned long long u64;
typedef unsigned int u32;

// --- exact-order helpers (no FMA contraction; must match f32 numpy reference) ---

__device__ __forceinline__ void decode_box(const float* __restrict__ roi,
                                           const float* __restrict__ dl,
                                           float& oy1, float& ox1,
                                           float& oy2, float& ox2) {
#pragma clang fp contract(off)
  float y1 = roi[0], x1 = roi[1], y2 = roi[2], x2 = roi[3];
  float h = y2 - y1;
  float w = x2 - x1;
  float cy = y1 + 0.5f * h;
  float cx = x1 + 0.5f * w;
  float d0 = dl[0] * 0.1f;
  float d1 = dl[1] * 0.1f;
  float d2 = dl[2] * 0.2f;
  float d3 = dl[3] * 0.2f;
  float ncy = d0 * h + cy;
  float ncx = d1 * w + cx;
  float nh = expf(d2) * h;
  float nw = expf(d3) * w;
  oy1 = ncy - 0.5f * nh;
  ox1 = ncx - 0.5f * nw;
  oy2 = ncy + 0.5f * nh;
  ox2 = ncx + 0.5f * nw;
}

__device__ __forceinline__ float area_f(float4 bx) {
#pragma clang fp contract(off)
  return (bx.z - bx.x) * (bx.w - bx.y);
}

// EXACT equivalent of: fl32(inter/den) > 0.5 (RNE), den>0 — see R6/R7 proof:
// collapses to (inter+inter) > den in plain f32.
__device__ __forceinline__ bool hit_f(float4 bi, float ia, float4 bj, float ja) {
#pragma clang fp contract(off)
  float yy1 = fmaxf(bi.x, bj.x);
  float xx1 = fmaxf(bi.y, bj.y);
  float yy2 = fminf(bi.z, bj.z);
  float xx2 = fminf(bi.w, bj.w);
  float ih = fmaxf(yy2 - yy1, 0.0f);
  float iw = fmaxf(xx2 - xx1, 0.0f);
  float inter = ih * iw;
  float den = ia + ja;
  den = den - inter;
  den = den + 1e-8f;
  return (inter + inter) > den;
}

// key packing: [63:32] score bits, [31:15] (131071-flat) so lower flat wins,
//              [14:5] n (payload only), [4:0] zero. Empty slot = 0.
__device__ __forceinline__ u64 pack_key(u32 sbits, int flat, int n) {
  return ((u64)sbits << 32) | ((u64)(131071 - flat) << 15) | ((u64)n << 5);
}

// exact rank of key k within its same-bucket run (counting-sort tie cleanup)
__device__ __forceinline__ int tie_rank(const u64* sk, int M, int p, u64 k) {
  int bkt = (int)((k >> 44) & (NBKT - 1));
  int gs = p, ge = p;
  while (gs > 0     && (int)((sk[gs - 1] >> 44) & (NBKT - 1)) == bkt) --gs;
  while (ge < M - 1 && (int)((sk[ge + 1] >> 44) & (NBKT - 1)) == bkt) ++ge;
  if (gs == ge) return p;
  int r = gs;
  for (int q = gs; q <= ge; ++q) r += (sk[q] > k) ? 1 : 0;  // keys unique
  return r;
}

// --- kernel 1: background rows (argmax over classes == 0), wave per row ---
__global__ __launch_bounds__(256) void bg_kernel(const float* __restrict__ probs,
                                                 int* __restrict__ bg) {
  int row = blockIdx.x * 4 + (threadIdx.x >> 6);
  int lane = threadIdx.x & 63;
  if (row >= NB * NROI) return;
  const float* p = probs + (size_t)row * NCLS;
  float m = -1e30f;
  for (int idx = 1 + lane; idx < NCLS; idx += 64) m = fmaxf(m, p[idx]);
  for (int off = 32; off; off >>= 1) m = fmaxf(m, __shfl_xor(m, off));
  if (lane == 0) bg[row] = (p[0] >= m) ? 1 : 0;  // argmax==0 iff p0 >= all others
}

// --- kernel 2: gather + counting sort + decode + register-resident greedy NMS ---
__global__ __launch_bounds__(NT) void gather_nms_kernel(
    const float* __restrict__ roi, const float* __restrict__ deltas,
    const float* __restrict__ probs, const int* __restrict__ bg,
    int* __restrict__ keep_count, u64* __restrict__ lane_key,
    int* __restrict__ bhist) {
  // XCD swizzle: 648 = 8*81; dispatch idx%8 = XCD -> XCD x owns batch x entirely
  int lane = (blockIdx.x % 8) * NCLS + blockIdx.x / 8;
  int b = lane / NCLS, c = lane % NCLS;
  int tid = threadIdx.x;
  int w = tid >> 6, l = tid & 63;

  // LDS: A [0,16K) sbox (skeyU aliases [0,8K), dead after scatter)
  //      B [16K,24K) skey sorted (live to end); C [24K,32K) bcnt[2048]
  __shared__ alignas(16) char smem[32768];
  float4* sbox  = (float4*)smem;
  u64*    skeyU = (u64*)smem;
  u64*    skey  = (u64*)(smem + 16384);
  int*    bcnt  = (int*)(smem + 24576);
  __shared__ u64 hmask_cur[64];
  __shared__ u64 keepmask[16];
  __shared__ u64 chunk_kept;
  __shared__ int scount, segbase[16], wsum[NW];

  if (tid == 0) scount = 0;
  if (tid < 64) hmask_cur[tid] = 0ull;
  if (tid < 16) keepmask[tid] = 0ull;
  for (int i = tid; i < NBKT; i += NT) bcnt[i] = 0;
  __syncthreads();

  // --- gather (score>0.5 && !bg) + 11-bit histogram ---
  for (int bn = 0; bn < NROI; bn += NT) {
    int n = bn + tid;
    bool cand = false; float s = 0.0f;
    if (n < NROI) {
      int row = b * NROI + n;
      s = probs[(size_t)row * NCLS + c];
      cand = (s > SCORE_T) && (bg[row] == 0);
    }
    u64 bal = __ballot(cand);
    int wb = 0;
    if (l == 0) wb = atomicAdd(&scount, (int)__popcll(bal));
    wb = __shfl(wb, 0);
    if (cand) {
      int off = (int)__popcll(bal & ((1ull << l) - 1ull));
      u32 sb = __float_as_uint(s);
      skeyU[wb + off] = ((u64)sb << 32) | (u64)(0xFFFFFFFFu - (u32)n);
      atomicAdd(&bcnt[(sb >> 12) & (NBKT - 1)], 1);  // scores in (0.5,1): monotone
    }
  }
  __syncthreads();
  int M = scount;                 // <= 1000
  int nchunks = (M + 63) >> 6;

  // --- counting-sort scan (descending): rank-space r -> bucket NBKT-1-r ---
  int q0 = bcnt[NBKT - 1 - (tid * 4 + 0)];
  int q1 = bcnt[NBKT - 1 - (tid * 4 + 1)];
  int q2 = bcnt[NBKT - 1 - (tid * 4 + 2)];
  int q3 = bcnt[NBKT - 1 - (tid * 4 + 3)];
  int tsum = q0 + q1 + q2 + q3;
  int inc = tsum;
  for (int off = 1; off < 64; off <<= 1) {
    int v = __shfl_up(inc, off);
    if (l >= off) inc += v;
  }
  if (l == 63) wsum[w] = inc;
  __syncthreads();                // also separates count-reads from start-writes
  int wbaseS = 0;
  for (int i = 0; i < w; ++i) wbaseS += wsum[i];
  int excl = wbaseS + inc - tsum;
  bcnt[NBKT - 1 - (tid * 4 + 0)] = excl;
  bcnt[NBKT - 1 - (tid * 4 + 1)] = excl + q0;
  bcnt[NBKT - 1 - (tid * 4 + 2)] = excl + q0 + q1;
  bcnt[NBKT - 1 - (tid * 4 + 3)] = excl + q0 + q1 + q2;
  __syncthreads();

  // --- scatter (arrival order within bucket; fixed next) ---
  for (int p = tid; p < M; p += NT) {
    u64 k = skeyU[p];
    int bkt = (int)((k >> 44) & (NBKT - 1));
    int pos = atomicAdd(&bcnt[bkt], 1);
    skey[pos] = k;
  }
  __syncthreads();

  // --- exact tie cleanup within same-bucket runs ---
  {
    u64 kA = 0, kB = 0; int npA = -1, npB = -1;
    int p0 = tid, p1 = tid + NT;
    if (p0 < M) { kA = skey[p0]; npA = tie_rank(skey, M, p0, kA); }
    if (p1 < M) { kB = skey[p1]; npB = tie_rank(skey, M, p1, kB); }
    __syncthreads();
    if (npA >= 0) skey[npA] = kA;
    if (npB >= 0) skey[npB] = kB;
  }
  __syncthreads();

  // --- decode sorted candidates into sbox (overwrites dead skeyU) ---
  for (int p = tid; p < M; p += NT) {
    u64 k = skey[p];
    u32 n = 0xFFFFFFFFu - (u32)(k & 0xFFFFFFFFull);
    int row = b * NROI + (int)n;
    float by1, bx1, by2, bx2;
    decode_box(roi + (size_t)row * 4, deltas + ((size_t)row * NCLS + c) * 4,
               by1, bx1, by2, bx2);
    sbox[p] = make_float4(by1, bx1, by2, bx2);
  }
  __syncthreads();

  // --- register-resident boxes: wave w owns chunks w (set0) and w+8 (set1) ---
  int j0 = (w << 6) + l, j1 = ((8 + w) << 6) + l;
  float4 bj0 = make_float4(0, 0, 0, 0), bj1 = bj0;
  float ja0 = 0.f, ja1 = 0.f;
  bool al0 = (j0 < M), al1 = (j1 < M);
  if (al0) { bj0 = sbox[j0]; ja0 = area_f(bj0); }
  if (al1) { bj1 = sbox[j1]; ja1 = area_f(bj1); }

  // --- chunked greedy NMS ---
  for (int ck = 0; ck < nchunks; ++ck) {
    if (ck > 0) {
      // sweep: apply km(ck-1)'s kept boxes to register boxes with j >= ck*64
      int ckp = ck - 1, end1 = ck << 6;
      u64 m2 = chunk_kept;
      bool t0 = al0 && (j0 >= end1), t1 = al1 && (j1 >= end1);
      while (m2) {
        if (!__ballot(t0 | t1)) break;          // wave fully dead/out-of-range
        int i = __ffsll((unsigned long long)m2) - 1;
        m2 &= m2 - 1;
        float4 bi = sbox[(ckp << 6) + i];       // broadcast
        float ia = area_f(bi);
        if (t0 && hit_f(bi, ia, bj0, ja0)) t0 = false;
        if (t1 && hit_f(bi, ia, bj1, ja1)) t1 = false;
      }
      if (j0 >= end1) al0 = t0;
      if (j1 >= end1) al1 = t1;
      // owner of chunk ck publishes pre-resolve alive mask
      if (w == (ck & 7)) {
        u64 bal = __ballot((ck >> 3) ? al1 : al0);
        if (l == 0) keepmask[ck] = bal;
      }
    } else {
      if (tid < 16) {   // chunk 0 pre-resolve alive = (p < M)
        int rem = M - (tid << 6);
        keepmask[tid] = (rem >= 64) ? ~0ull : ((rem <= 0) ? 0ull : ((1ull << rem) - 1ull));
      }
    }

    // map: 64x64 intra-chunk hit matrix, 8 rows per wave, per-lane column masks
    {
      float4 bL = sbox[(ck << 6) + l];          // coalesced; garbage >=M masked later
      float aL = area_f(bL);
      u64 part = 0;
#pragma unroll
      for (int r = 0; r < 8; ++r) {
        int i = (w << 3) + r;
        float4 bi = sbox[(ck << 6) + i];        // broadcast
        float ia = area_f(bi);
        if (hit_f(bi, ia, bL, aL)) part |= (1ull << i);
      }
      atomicOr((unsigned long long*)&hmask_cur[l], (unsigned long long)part);
    }
    __syncthreads();   // keepmask[ck] + hmask_cur complete

    // resolve (wave 0): proven ballot greedy on precomputed masks
    if (w == 0) {
      u64 kw = keepmask[ck];
      u64 myrow = hmask_cur[l];                 // bit i = hit(box_i, box_l)
      hmask_cur[l] = 0ull;                      // re-zero for next chunk
      bool alive = (kw >> l) & 1;
      u64 mask = alive ? (myrow & ((1ull << l) - 1ull)) : 0ull;
      u64 rem = ~__ballot(alive);
      for (int i = 0; i < 63; ++i) {
        if (!((rem >> i) & 1)) rem |= __ballot((mask >> i) & 1);  // uniform branch
      }
      bool kept = alive && !((rem >> l) & 1);
      u64 km = __ballot(kept);
      if (l == 0) { keepmask[ck] = km; chunk_kept = km; }
    }
    __syncthreads();   // km published; hmask_cur zeroed
  }

  // --- parallel compaction + fused per-batch 13-bit histogram ---
  if (tid < 16) {
    int acc = 0;
    for (int i = 0; i < tid; ++i) acc += (int)__popcll(keepmask[i]);
    segbase[tid] = acc;
  }
  __syncthreads();
  int total = segbase[15] + (int)__popcll(keepmask[15]);
  for (int s = 0; s < 2; ++s) {
    int seg = (w << 1) + s;
    u64 word = keepmask[seg];
    int p = (seg << 6) + l;
    if ((word >> l) & 1) {
      int rank = segbase[seg] + (int)__popcll(word & ((1ull << l) - 1ull));
      if (rank < MAXKEEP) {
        u64 k = skey[p];
        u32 sbits = (u32)(k >> 32);
        int n = (int)(0xFFFFFFFFu - (u32)(k & 0xFFFFFFFFull));
        lane_key[(size_t)lane * MAXKEEP + rank] = pack_key(sbits, c * NROI + p, n);
        atomicAdd(&bhist[b * HSIZE + (int)((sbits >> 10) & (HSIZE - 1))], 1);
      }
    }
  }
  if (tid == 0) keep_count[lane] = min(total, MAXKEEP);
}

// --- kernel 3: per-batch parallel top-200 (radix-select + bitonic), exact order ---
__global__ __launch_bounds__(512) void merge_kernel(
    const float* __restrict__ roi, const float* __restrict__ deltas,
    const int* __restrict__ keep_count, const u64* __restrict__ lane_key,
    const int* __restrict__ bhist,
    float* __restrict__ out_b, float* __restrict__ out_c, float* __restrict__ out_s) {
  int b = blockIdx.x;    // 8 blocks; idx%8 = XCD that produced batch b's keys
  int tid = threadIdx.x;

  __shared__ int hist[HSIZE];
  __shared__ int csum[256];
  __shared__ int cnts[NCLS];
  __shared__ int tb_sh, scnt_sh;
  __shared__ u64 surv[SCAP];

  for (int i = tid; i < HSIZE; i += 512) hist[i] = bhist[b * HSIZE + i];
  for (int i = tid; i < NCLS; i += 512) cnts[i] = keep_count[b * NCLS + i];
  if (tid == 0) { tb_sh = 0; scnt_sh = 0; }
  __syncthreads();

  // suffix sums; find tb = max bucket with sufsum >= 200 (0 if total < 200)
  int base = tid * 32;
  if (tid < 256) {
    int psum = 0;
    for (int i = 0; i < 32; ++i) psum += hist[base + i];
    csum[tid] = psum;
  }
  __syncthreads();
  if (tid == 0) {
    int acc = 0;
    for (int t = 255; t >= 0; --t) { acc += csum[t]; csum[t] = acc; }
  }
  __syncthreads();
  if (tid < 256) {
    int acc = (tid < 255) ? csum[tid + 1] : 0;
    int local_tb = -1;
    for (int i = 31; i >= 0; --i) {
      acc += hist[base + i];
      if (acc >= MAXKEEP && local_tb < 0) local_tb = base + i;
    }
    if (local_tb >= 0) atomicMax(&tb_sh, local_tb);
  }
  __syncthreads();
  int tb = tb_sh;

  // gather survivors (all keys in buckets >= tb; superset of exact top-200)
  for (int s = tid; s < NCLS * MAXKEEP; s += 512) {
    int c = s / MAXKEEP, h = s % MAXKEEP;
    if (h < cnts[c]) {
      u64 k = lane_key[((size_t)(b * NCLS + c)) * MAXKEEP + h];
      u32 sb = (u32)(k >> 32);
      if ((int)((sb >> 10) & (HSIZE - 1)) >= tb) {
        int pos = atomicAdd(&scnt_sh, 1);
        if (pos < SCAP) surv[pos] = k;
      }
    }
  }
  __syncthreads();
  int scnt = min(scnt_sh, SCAP);
  int size = 2;
  while (size < scnt) size <<= 1;
  for (int i = scnt + tid; i < size; i += 512) surv[i] = 0ull;
  __syncthreads();

  // bitonic sort descending by full key (score desc, flat asc)
  for (int k2 = 2; k2 <= size; k2 <<= 1) {
    for (int j = k2 >> 1; j > 0; j >>= 1) {
      for (int i = tid; i < size; i += 512) {
        int ixj = i ^ j;
        if (ixj > i) {
          u64 a = surv[i], bb = surv[ixj];
          bool swp = ((i & k2) == 0) ? (a < bb) : (a > bb);
          if (swp) { surv[i] = bb; surv[ixj] = a; }
        }
      }
      __syncthreads();
    }
  }

  // decode + write top-200 in parallel; zero-fill the rest
  for (int t = tid; t < MAXKEEP; t += 512) {
    size_t ob = ((size_t)b * MAXKEEP + t) * 4;
    if (t < scnt) {
      u64 k = surv[t];
      int flat = 131071 - (int)((k >> 15) & 0x1FFFF);
      int c = flat / NROI;
      int n = (int)((k >> 5) & 0x3FF);
      int row = b * NROI + n;
      float by1, bx1, by2, bx2;
      decode_box(roi + (size_t)row * 4, deltas + ((size_t)row * NCLS + c) * 4,
                 by1, bx1, by2, bx2);
      out_b[ob + 0] = fminf(fmaxf(by1, 0.0f), 1.0f);
      out_b[ob + 1] = fminf(fmaxf(bx1, 0.0f), 1.0f);
      out_b[ob + 2] = fminf(fmaxf(by2, 0.0f), 1.0f);
      out_b[ob + 3] = fminf(fmaxf(bx2, 0.0f), 1.0f);
      out_c[b * MAXKEEP + t] = (float)c;
      out_s[b * MAXKEEP + t] = __uint_as_float((u32)(k >> 32));
    } else {
      out_b[ob + 0] = 0.0f; out_b[ob + 1] = 0.0f;
      out_b[ob + 2] = 0.0f; out_b[ob + 3] = 0.0f;
      out_c[b * MAXKEEP + t] = 0.0f;
      out_s[b * MAXKEEP + t] = 0.0f;
    }
  }
}

extern "C" void kernel_launch(void* const* d_in, const int* in_sizes, int n_in,
                              void* d_out, int out_size, void* d_ws, size_t ws_size,
                              hipStream_t stream) {
  const float* roi    = (const float*)d_in[0];  // [8,1000,4]
  const float* deltas = (const float*)d_in[1];  // [8,1000,324]
  const float* probs  = (const float*)d_in[2];  // [8,1000,81]

  char* ws = (char*)d_ws;
  int* bg         = (int*)(ws);                   // 32000 B
  int* keep_count = (int*)(ws + 32768);           // 2592 B
  int* bhist      = (int*)(ws + 40960);           // 8*8192*4 = 262144 B
  u64* lane_key   = (u64*)(ws + 40960 + 262144);  // 648*200*8 = 1,036,800 B

  float* out_b = (float*)d_out;                 // [8,200,4]
  float* out_c = out_b + NB * MAXKEEP * 4;      // [8,200]
  float* out_s = out_c + NB * MAXKEEP;          // [8,200]

  hipMemsetAsync(bhist, 0, NB * HSIZE * sizeof(int), stream);
  bg_kernel<<<(NB * NROI + 3) / 4, 256, 0, stream>>>(probs, bg);
  gather_nms_kernel<<<NLANE, NT, 0, stream>>>(roi, deltas, probs, bg,
                                              keep_count, lane_key, bhist);
  merge_kernel<<<NB, 512, 0, stream>>>(roi, deltas, keep_count, lane_key, bhist,
                                       out_b, out_c, out_s);
}

// Round 9
// 157.464 us; speedup vs baseline: 1.3100x; 1.3100x over previous
//
#include <hip/hip_runtime.h>

#define NROI 1000
#define NCLS 81
#define NB   8
#define NLANE (NB*NCLS)        // 648 = 8 XCDs * 81
#define MAXM 1024
#define MAXKEEP 200
#define SCORE_T 0.5f
#define NT 512
#define NW 8                   // waves per block
#define HBITS 13
#define HSIZE (1<<HBITS)       // 8192 merge buckets
#define SCAP 1024

typedef unsigned long long u64;
typedef unsigned int u32;

// --- exact-order helpers (no FMA contraction; must match f32 numpy reference) ---

__device__ __forceinline__ void decode_box(const float* __restrict__ roi,
                                           const float* __restrict__ dl,
                                           float& oy1, float& ox1,
                                           float& oy2, float& ox2) {
#pragma clang fp contract(off)
  float y1 = roi[0], x1 = roi[1], y2 = roi[2], x2 = roi[3];
  float h = y2 - y1;
  float w = x2 - x1;
  float cy = y1 + 0.5f * h;
  float cx = x1 + 0.5f * w;
  float d0 = dl[0] * 0.1f;
  float d1 = dl[1] * 0.1f;
  float d2 = dl[2] * 0.2f;
  float d3 = dl[3] * 0.2f;
  float ncy = d0 * h + cy;
  float ncx = d1 * w + cx;
  float nh = expf(d2) * h;
  float nw = expf(d3) * w;
  oy1 = ncy - 0.5f * nh;
  ox1 = ncx - 0.5f * nw;
  oy2 = ncy + 0.5f * nh;
  ox2 = ncx + 0.5f * nw;
}

__device__ __forceinline__ float area_f(float4 bx) {
#pragma clang fp contract(off)
  return (bx.z - bx.x) * (bx.w - bx.y);
}

// EXACT equivalent of: fl32(inter/den) > 0.5 (RNE), den>0 — proof in R6/R7:
// collapses to (inter+inter) > den in plain f32.
__device__ __forceinline__ bool hit_f(float4 bi, float ia, float4 bj, float ja) {
#pragma clang fp contract(off)
  float yy1 = fmaxf(bi.x, bj.x);
  float xx1 = fmaxf(bi.y, bj.y);
  float yy2 = fminf(bi.z, bj.z);
  float xx2 = fminf(bi.w, bj.w);
  float ih = fmaxf(yy2 - yy1, 0.0f);
  float iw = fmaxf(xx2 - xx1, 0.0f);
  float inter = ih * iw;
  float den = ia + ja;
  den = den - inter;
  den = den + 1e-8f;
  return (inter + inter) > den;
}

// key packing: [63:32] score bits, [31:15] (131071-flat) so lower flat wins,
//              [14:5] n (payload only), [4:0] zero. Empty slot = 0.
__device__ __forceinline__ u64 pack_key(u32 sbits, int flat, int n) {
  return ((u64)sbits << 32) | ((u64)(131071 - flat) << 15) | ((u64)n << 5);
}

// --- kernel 1: background rows (argmax over classes == 0), wave per row ---
__global__ __launch_bounds__(256) void bg_kernel(const float* __restrict__ probs,
                                                 int* __restrict__ bg) {
  int row = blockIdx.x * 4 + (threadIdx.x >> 6);
  int lane = threadIdx.x & 63;
  if (row >= NB * NROI) return;
  const float* p = probs + (size_t)row * NCLS;
  float m = -1e30f;
  for (int idx = 1 + lane; idx < NCLS; idx += 64) m = fmaxf(m, p[idx]);
  for (int off = 32; off; off >>= 1) m = fmaxf(m, __shfl_xor(m, off));
  if (lane == 0) bg[row] = (p[0] >= m) ? 1 : 0;  // argmax==0 iff p0 >= all others
}

// --- kernel 2 (fused): gather + rank-sort + decode + reg-cached greedy NMS ---
__global__ __launch_bounds__(NT) void gather_nms_kernel(
    const float* __restrict__ roi, const float* __restrict__ deltas,
    const float* __restrict__ probs, const int* __restrict__ bg,
    int* __restrict__ keep_count, u64* __restrict__ lane_key,
    int* __restrict__ bhist) {
  // XCD swizzle: 648 = 8*81; dispatch idx%8 = XCD -> XCD x owns batch x entirely
  int lane = (blockIdx.x % 8) * NCLS + blockIdx.x / 8;
  int b = lane / NCLS, c = lane % NCLS;
  int tid = threadIdx.x;
  int w = tid >> 6, l = tid & 63;

  // smem: [0,16K) sbox (alias: skeyU in [0,8K+8], dead after sort)
  //       [16K,24K) hmask; [24K,32K) skey (sorted, live to the end)
  __shared__ alignas(16) char smem[32768];
  float4*     sbox   = (float4*)smem;
  u64*        skeyU  = (u64*)smem;
  ulonglong2* skeyU2 = (ulonglong2*)smem;
  u64*        hmask  = (u64*)(smem + 16384);
  u64*        skey   = (u64*)(smem + 24576);
  __shared__ u64 keepmask[16];
  __shared__ u64 chunk_kept;
  __shared__ int scount, segbase[16];

  if (tid == 0) scount = 0;
  __syncthreads();

  // --- gather: score > 0.5 && !bg (ballot-aggregated append; M <= 1000) ---
  for (int base_n = 0; base_n < NROI; base_n += NT) {
    int n = base_n + tid;
    bool cand = false;
    float s = 0.0f;
    if (n < NROI) {
      int row = b * NROI + n;
      s = probs[(size_t)row * NCLS + c];
      cand = (s > SCORE_T) && (bg[row] == 0);
    }
    u64 bal = __ballot(cand);
    int wb = 0;
    if (l == 0) wb = atomicAdd(&scount, (int)__popcll(bal));
    wb = __shfl(wb, 0);
    if (cand) {
      int off = (int)__popcll(bal & ((1ull << l) - 1ull));
      skeyU[wb + off] = ((u64)__float_as_uint(s) << 32) | (u64)(0xFFFFFFFFu - (u32)n);
    }
  }
  __syncthreads();
  int M = scount;          // <= 1000
  if (tid == 0) skeyU[M] = 0ull;   // pad so the b128-packed q-loop is safe
  __syncthreads();
  int Mh = (M + 1) >> 1;

  // --- rank sort: keys unique -> rank is a permutation; b128 = 2 keys/read ---
  if (M <= NT) {           // block-uniform fast path: 1 key/thread
    u64 k0 = (tid < M) ? skeyU[tid] : 0ull;
    int r0 = 0;
    for (int q = 0; q < Mh; ++q) {   // broadcast reads, conflict-free
      ulonglong2 kq = skeyU2[q];
      r0 += (kq.x > k0);
      r0 += (kq.y > k0);
    }
    if (tid < 16) {
      int rem = M - (tid << 6);
      keepmask[tid] = (rem >= 64) ? ~0ull : ((rem <= 0) ? 0ull : ((1ull << rem) - 1ull));
    }
    if (tid < M) skey[r0] = k0;
  } else {                 // 2 keys/thread
    u64 k0 = skeyU[tid];
    u64 k1 = (tid + NT < M) ? skeyU[tid + NT] : 0ull;
    int r0 = 0, r1 = 0;
    for (int q = 0; q < Mh; ++q) {
      ulonglong2 kq = skeyU2[q];
      r0 += (kq.x > k0); r0 += (kq.y > k0);
      r1 += (kq.x > k1); r1 += (kq.y > k1);
    }
    if (tid < 16) {
      int rem = M - (tid << 6);
      keepmask[tid] = (rem >= 64) ? ~0ull : ((rem <= 0) ? 0ull : ((1ull << rem) - 1ull));
    }
    skey[r0] = k0;
    if (tid + NT < M) skey[r1] = k1;
  }
  __syncthreads();   // all skeyU reads done; skey ready

  // --- decode sorted candidates into sbox (overwrites dead skeyU region) ---
  for (int p = tid; p < M; p += NT) {
    u64 k = skey[p];
    u32 n = 0xFFFFFFFFu - (u32)(k & 0xFFFFFFFFull);
    int row = b * NROI + (int)n;
    float by1, bx1, by2, bx2;
    decode_box(roi + (size_t)row * 4, deltas + ((size_t)row * NCLS + c) * 4,
               by1, bx1, by2, bx2);
    sbox[p] = make_float4(by1, bx1, by2, bx2);
  }

  // --- chunked greedy NMS: reg-cached chunk boxes + ballot masks ---
  int nchunks = (M + 63) >> 6;
  for (int ck = 0; ck < nchunks; ++ck) {
    int start = ck << 6;
    __syncthreads();   // A: decode done / prev step3 done; hmask free

    // every wave's lane l caches chunk box start+l (garbage beyond M: masked)
    float4 bi = sbox[start + l];
    float ia = area_f(bi);

    // step 1: wave-parallel hit masks; 8 waves split j; unconditional body
    // (no data-dependent branch -> compiler software-pipelines the loop)
    for (int j = start + w; j < M; j += NW) {
      float4 bj = sbox[j];             // broadcast (same addr all lanes)
      float ja = area_f(bj);           // recompute: 3 VALU, saves a b32 broadcast
      bool h = hit_f(bi, ia, bj, ja);
      u64 bal = __ballot(h);
      if (l == 0) hmask[j] = bal;
    }
    __syncthreads();   // B: hmask ready

    // step 2 (wave 0): serial ballot resolve on precomputed bits
    if (tid < 64) {
      u64 kw = keepmask[ck];
      bool alive = (kw >> l) & 1;
      u64 mask = alive ? (hmask[start + l] & ((1ull << l) - 1ull)) : 0ull;
      u64 rem = ~__ballot(alive);
      for (int i = 0; i < 63; ++i) {
        if (!((rem >> i) & 1)) rem |= __ballot((mask >> i) & 1);  // uniform branch
      }
      bool kept = alive && !((rem >> l) & 1);
      u64 km = __ballot(kept);
      if (l == 0) { keepmask[ck] = km; chunk_kept = km; }
    }
    __syncthreads();   // C: chunk_kept + chunk keep word final

    // step 3: cross-chunk suppression; one 64-j group per wave round-robin
    u64 km = chunk_kept;
    for (int g = ck + 1 + w; g < nchunks; g += NW) {
      u64 kw = keepmask[g];
      if (kw == 0ull) continue;        // wave-uniform
      int j = (g << 6) + l;            // kw bit l set implies j < M
      bool supp = ((kw >> l) & 1) && (hmask[j] & km);
      u64 sb = __ballot(supp);
      if (l == 0 && sb) keepmask[g] = kw & ~sb;
    }
  }
  __syncthreads();

  // --- parallel compaction + fused per-batch 13-bit histogram ---
  if (tid < 16) {
    int acc = 0;
    for (int i = 0; i < tid; ++i) acc += (int)__popcll(keepmask[i]);
    segbase[tid] = acc;
  }
  __syncthreads();
  int total = segbase[15] + (int)__popcll(keepmask[15]);
  for (int s = 0; s < 2; ++s) {
    int seg = (w << 1) + s;
    u64 word = keepmask[seg];
    int p = (seg << 6) + l;
    if ((word >> l) & 1) {
      int rank = segbase[seg] + (int)__popcll(word & ((1ull << l) - 1ull));
      if (rank < MAXKEEP) {
        u64 k = skey[p];
        u32 sbits = (u32)(k >> 32);
        int n = (int)(0xFFFFFFFFu - (u32)(k & 0xFFFFFFFFull));
        lane_key[(size_t)lane * MAXKEEP + rank] = pack_key(sbits, c * NROI + p, n);
        atomicAdd(&bhist[b * HSIZE + (int)((sbits >> 10) & (HSIZE - 1))], 1);
      }
    }
  }
  if (tid == 0) keep_count[lane] = min(total, MAXKEEP);
}

// --- kernel 3: per-batch parallel top-200 (radix-select + bitonic), exact order ---
__global__ __launch_bounds__(512) void merge_kernel(
    const float* __restrict__ roi, const float* __restrict__ deltas,
    const int* __restrict__ keep_count, const u64* __restrict__ lane_key,
    const int* __restrict__ bhist,
    float* __restrict__ out_b, float* __restrict__ out_c, float* __restrict__ out_s) {
  int b = blockIdx.x;    // 8 blocks; idx%8 = XCD that produced batch b's keys
  int tid = threadIdx.x;

  __shared__ int hist[HSIZE];
  __shared__ int csum[256];
  __shared__ int cnts[NCLS];
  __shared__ int tb_sh, scnt_sh;
  __shared__ u64 surv[SCAP];

  for (int i = tid; i < HSIZE; i += 512) hist[i] = bhist[b * HSIZE + i];
  for (int i = tid; i < NCLS; i += 512) cnts[i] = keep_count[b * NCLS + i];
  if (tid == 0) { tb_sh = 0; scnt_sh = 0; }
  __syncthreads();

  // suffix sums; find tb = max bucket with sufsum >= 200 (0 if total < 200)
  int base = tid * 32;
  if (tid < 256) {
    int psum = 0;
    for (int i = 0; i < 32; ++i) psum += hist[base + i];
    csum[tid] = psum;
  }
  __syncthreads();
  if (tid == 0) {
    int acc = 0;
    for (int t = 255; t >= 0; --t) { acc += csum[t]; csum[t] = acc; }
  }
  __syncthreads();
  if (tid < 256) {
    int acc = (tid < 255) ? csum[tid + 1] : 0;
    int local_tb = -1;
    for (int i = 31; i >= 0; --i) {
      acc += hist[base + i];
      if (acc >= MAXKEEP && local_tb < 0) local_tb = base + i;
    }
    if (local_tb >= 0) atomicMax(&tb_sh, local_tb);
  }
  __syncthreads();
  int tb = tb_sh;

  // gather survivors (all keys in buckets >= tb; superset of exact top-200)
  for (int s = tid; s < NCLS * MAXKEEP; s += 512) {
    int c = s / MAXKEEP, h = s % MAXKEEP;
    if (h < cnts[c]) {
      u64 k = lane_key[((size_t)(b * NCLS + c)) * MAXKEEP + h];
      u32 sb = (u32)(k >> 32);
      if ((int)((sb >> 10) & (HSIZE - 1)) >= tb) {
        int pos = atomicAdd(&scnt_sh, 1);
        if (pos < SCAP) surv[pos] = k;
      }
    }
  }
  __syncthreads();
  int scnt = min(scnt_sh, SCAP);
  int size = 2;
  while (size < scnt) size <<= 1;
  for (int i = scnt + tid; i < size; i += 512) surv[i] = 0ull;
  __syncthreads();

  // bitonic sort descending by full key (score desc, flat asc)
  for (int k2 = 2; k2 <= size; k2 <<= 1) {
    for (int j = k2 >> 1; j > 0; j >>= 1) {
      for (int i = tid; i < size; i += 512) {
        int ixj = i ^ j;
        if (ixj > i) {
          u64 a = surv[i], bb = surv[ixj];
          bool swp = ((i & k2) == 0) ? (a < bb) : (a > bb);
          if (swp) { surv[i] = bb; surv[ixj] = a; }
        }
      }
      __syncthreads();
    }
  }

  // decode + write top-200 in parallel; zero-fill the rest
  for (int t = tid; t < MAXKEEP; t += 512) {
    size_t ob = ((size_t)b * MAXKEEP + t) * 4;
    if (t < scnt) {
      u64 k = surv[t];
      int flat = 131071 - (int)((k >> 15) & 0x1FFFF);
      int c = flat / NROI;
      int n = (int)((k >> 5) & 0x3FF);
      int row = b * NROI + n;
      float by1, bx1, by2, bx2;
      decode_box(roi + (size_t)row * 4, deltas + ((size_t)row * NCLS + c) * 4,
                 by1, bx1, by2, bx2);
      out_b[ob + 0] = fminf(fmaxf(by1, 0.0f), 1.0f);
      out_b[ob + 1] = fminf(fmaxf(bx1, 0.0f), 1.0f);
      out_b[ob + 2] = fminf(fmaxf(by2, 0.0f), 1.0f);
      out_b[ob + 3] = fminf(fmaxf(bx2, 0.0f), 1.0f);
      out_c[b * MAXKEEP + t] = (float)c;
      out_s[b * MAXKEEP + t] = __uint_as_float((u32)(k >> 32));
    } else {
      out_b[ob + 0] = 0.0f; out_b[ob + 1] = 0.0f;
      out_b[ob + 2] = 0.0f; out_b[ob + 3] = 0.0f;
      out_c[b * MAXKEEP + t] = 0.0f;
      out_s[b * MAXKEEP + t] = 0.0f;
    }
  }
}

extern "C" void kernel_launch(void* const* d_in, const int* in_sizes, int n_in,
                              void* d_out, int out_size, void* d_ws, size_t ws_size,
                              hipStream_t stream) {
  const float* roi    = (const float*)d_in[0];  // [8,1000,4]
  const float* deltas = (const float*)d_in[1];  // [8,1000,324]
  const float* probs  = (const float*)d_in[2];  // [8,1000,81]

  char* ws = (char*)d_ws;
  int* bg         = (int*)(ws);                   // 32000 B
  int* keep_count = (int*)(ws + 32768);           // 2592 B
  int* bhist      = (int*)(ws + 40960);           // 8*8192*4 = 262144 B
  u64* lane_key   = (u64*)(ws + 40960 + 262144);  // 648*200*8 = 1,036,800 B

  float* out_b = (float*)d_out;                 // [8,200,4]
  float* out_c = out_b + NB * MAXKEEP * 4;      // [8,200]
  float* out_s = out_c + NB * MAXKEEP;          // [8,200]

  hipMemsetAsync(bhist, 0, NB * HSIZE * sizeof(int), stream);
  bg_kernel<<<(NB * NROI + 3) / 4, 256, 0, stream>>>(probs, bg);
  gather_nms_kernel<<<NLANE, NT, 0, stream>>>(roi, deltas, probs, bg,
                                              keep_count, lane_key, bhist);
  merge_kernel<<<NB, 512, 0, stream>>>(roi, deltas, keep_count, lane_key, bhist,
                                       out_b, out_c, out_s);
}